// Round 5
// baseline (1478.811 us; speedup 1.0000x reference)
//
#include <hip/hip_runtime.h>
#include <cstdint>
#include <cstddef>

#define D 64
#define D_FEAT 128
#define SLOPE 0.01f
#define BSH 7                 // bucket = dst >> 7  (128 nodes per bucket)
#define BW 128
#define ACCS 68               // padded LDS row stride (floats) -> bank spread by row

typedef __attribute__((ext_vector_type(8))) short bf16x8;
typedef __attribute__((ext_vector_type(4))) float f32x4;

__device__ __forceinline__ float leaky(float v) { return v >= 0.f ? v : SLOPE * v; }

__device__ __forceinline__ unsigned short f2bf(float f) {
    union { float f; unsigned u; } v; v.f = f;
    unsigned r = v.u + 0x7FFF + ((v.u >> 16) & 1);   // RNE
    return (unsigned short)(r >> 16);
}
__device__ __forceinline__ float bf2f(unsigned short b) {
    union { unsigned u; float f; } v; v.u = ((unsigned)b) << 16;
    return v.f;
}

// B-fragment of row-major fp32 W[K][64] for 16x16x32 MFMA
__device__ __forceinline__ bf16x8 wfrag(const float* W, int ks, int nt, int lane) {
    int col = nt * 16 + (lane & 15);
    int k0 = ks * 32 + ((lane >> 4) << 3);
    bf16x8 r;
#pragma unroll
    for (int j = 0; j < 8; ++j)
        r[j] = (short)f2bf(W[(k0 + j) * 64 + col]);
    return r;
}

// ---------------- bucket histogram (LDS-staged) ----------------
__global__ __launch_bounds__(256) void k_bhist(const int* __restrict__ edst,
    int* __restrict__ bcnt, int E, int nbk)
{
    __shared__ int h[1024];
    for (int i = threadIdx.x; i < 1024; i += 256) h[i] = 0;
    __syncthreads();
    int base = blockIdx.x * 4096;
    for (int i = threadIdx.x; i < 4096; i += 256) {
        int e = base + i;
        if (e < E) atomicAdd(&h[edst[e] >> BSH], 1);
    }
    __syncthreads();
    for (int i = threadIdx.x; i < nbk; i += 256)
        if (h[i]) atomicAdd(&bcnt[i], h[i]);
}

// ---------------- single-block exclusive scan of bucket counts ----------------
__global__ __launch_bounds__(1024) void k_bscan(const int* __restrict__ bcnt,
    int* __restrict__ bstart, int* __restrict__ gcur, int nbk)
{
    __shared__ int t[1024];
    int tid = threadIdx.x;
    int v = (tid < nbk) ? bcnt[tid] : 0;
    t[tid] = v;
    __syncthreads();
    for (int d = 1; d < 1024; d <<= 1) {
        int x = t[tid];
        int a = (tid >= d) ? t[tid - d] : 0;
        __syncthreads();
        t[tid] = x + a;
        __syncthreads();
    }
    int ex = tid ? t[tid - 1] : 0;
    if (tid < nbk) { bstart[tid] = ex; gcur[tid] = ex; }
    if (tid == 1023) bstart[nbk] = t[1023];
}

// ---------------- partition edges into buckets, packed (dloc<<25 | src) -------
__global__ __launch_bounds__(256) void k_part(const int* __restrict__ esrc,
    const int* __restrict__ edst, int* __restrict__ gcur,
    unsigned* __restrict__ pairs, int E)
{
    __shared__ int lcnt[1024];
    __shared__ int lbase[1024];
    int base = blockIdx.x * 4096;
    for (int i = threadIdx.x; i < 1024; i += 256) lcnt[i] = 0;
    __syncthreads();
    int dv[16];
#pragma unroll
    for (int i = 0; i < 16; ++i) {
        int e = base + i * 256 + threadIdx.x;
        if (e < E) {
            dv[i] = edst[e];
            atomicAdd(&lcnt[dv[i] >> BSH], 1);
        } else dv[i] = -1;
    }
    __syncthreads();
    for (int i = threadIdx.x; i < 1024; i += 256) {
        int c = lcnt[i];
        lbase[i] = c ? atomicAdd(&gcur[i], c) : 0;
    }
    __syncthreads();
    for (int i = threadIdx.x; i < 1024; i += 256) lcnt[i] = 0;
    __syncthreads();
#pragma unroll
    for (int i = 0; i < 16; ++i) {
        if (dv[i] >= 0) {
            int e = base + i * 256 + threadIdx.x;
            int b = dv[i] >> BSH;
            int r = atomicAdd(&lcnt[b], 1);
            unsigned pk = ((unsigned)(dv[i] & (BW - 1)) << 25) | (unsigned)esrc[e];
            pairs[lbase[b] + r] = pk;
        }
    }
}

// ---------------- fused gather: block per bucket, LDS fp32 accumulate --------
__global__ __launch_bounds__(256) void k_gather(const unsigned* __restrict__ pairs,
    const int* __restrict__ bstart, const unsigned short* __restrict__ Xb,
    unsigned short* __restrict__ Ab, int N)
{
    __shared__ float acc[BW * ACCS];   // 34 KB
    int b = blockIdx.x;
    int node0 = b << BSH;
    int s0 = bstart[b], s1 = bstart[b + 1];
    for (int i = threadIdx.x; i < BW * ACCS / 4; i += 256)
        ((float4*)acc)[i] = (float4){0.f, 0.f, 0.f, 0.f};
    __syncthreads();
    int g = threadIdx.x >> 4;          // 16 groups of 16 lanes, one edge each
    int li = threadIdx.x & 15;
    for (int e = s0 + g; e < s1; e += 16) {
        unsigned p = pairs[e];         // same addr across group -> broadcast
        int src = (int)(p & 0x1FFFFFFu);
        int dl = (int)(p >> 25);
        uint2 u = *(const uint2*)(Xb + (size_t)src * D + li * 4);
        float* ap = acc + dl * ACCS + li * 4;
        atomicAdd(ap + 0, bf2f((unsigned short)(u.x & 0xFFFFu)));
        atomicAdd(ap + 1, bf2f((unsigned short)(u.x >> 16)));
        atomicAdd(ap + 2, bf2f((unsigned short)(u.y & 0xFFFFu)));
        atomicAdd(ap + 3, bf2f((unsigned short)(u.y >> 16)));
    }
    __syncthreads();
    // writeback bf16, coalesced (32 uints per row)
    for (int i = threadIdx.x; i < BW * 32; i += 256) {
        int row = i >> 5;
        int node = node0 + row;
        if (node < N) {
            int c2 = (i & 31) * 2;
            float a0 = acc[row * ACCS + c2];
            float a1 = acc[row * ACCS + c2 + 1];
            unsigned o = (unsigned)f2bf(a0) | ((unsigned)f2bf(a1) << 16);
            *(unsigned*)(Ab + (size_t)node * D + c2) = o;
        }
    }
}

// ---------------- MLP + L2 norm (MFMA), fp32 in -> bf16 out ----------------
__global__ __launch_bounds__(256) void k_mlp(const float* __restrict__ F,
    const float* __restrict__ Wm, const float* __restrict__ bm,
    unsigned short* __restrict__ Xb, int N)
{
    int lane = threadIdx.x & 63, w = threadIdx.x >> 6;
    int cl = lane & 15, g = lane >> 4;
    int ntiles = (N + 63) / 64;

    bf16x8 Wmf[4][4];
#pragma unroll
    for (int ks = 0; ks < 4; ++ks)
#pragma unroll
        for (int nt = 0; nt < 4; ++nt)
            Wmf[ks][nt] = wfrag(Wm, ks, nt, lane);
    float bmv[4];
#pragma unroll
    for (int nt = 0; nt < 4; ++nt) bmv[nt] = bm[nt * 16 + cl];

    for (int tb = blockIdx.x; tb < ntiles; tb += gridDim.x) {
        int node0 = tb * 64 + w * 16;
        if (node0 >= N) continue;
        f32x4 acc[4];
#pragma unroll
        for (int nt = 0; nt < 4; ++nt) acc[nt] = (f32x4){0.f, 0.f, 0.f, 0.f};
#pragma unroll
        for (int ks = 0; ks < 4; ++ks) {
            const float4* fp = (const float4*)(F + (size_t)(node0 + cl) * D_FEAT + ks * 32 + g * 8);
            float4 a = fp[0], b = fp[1];
            bf16x8 af;
            af[0] = (short)f2bf(a.x); af[1] = (short)f2bf(a.y);
            af[2] = (short)f2bf(a.z); af[3] = (short)f2bf(a.w);
            af[4] = (short)f2bf(b.x); af[5] = (short)f2bf(b.y);
            af[6] = (short)f2bf(b.z); af[7] = (short)f2bf(b.w);
#pragma unroll
            for (int nt = 0; nt < 4; ++nt)
                acc[nt] = __builtin_amdgcn_mfma_f32_16x16x32_bf16(af, Wmf[ks][nt], acc[nt], 0, 0, 0);
        }
        float ss[4] = {0.f, 0.f, 0.f, 0.f};
#pragma unroll
        for (int nt = 0; nt < 4; ++nt)
#pragma unroll
            for (int i = 0; i < 4; ++i) {
                float v = acc[nt][i] + bmv[nt];
                acc[nt][i] = v;
                ss[i] += v * v;
            }
#pragma unroll
        for (int off = 8; off >= 1; off >>= 1)
#pragma unroll
            for (int i = 0; i < 4; ++i)
                ss[i] += __shfl_xor(ss[i], off);
        float inv[4];
#pragma unroll
        for (int i = 0; i < 4; ++i)
            inv[i] = 1.f / fmaxf(sqrtf(ss[i]), 1e-12f);
#pragma unroll
        for (int nt = 0; nt < 4; ++nt)
#pragma unroll
            for (int i = 0; i < 4; ++i)
                Xb[(size_t)(node0 + g * 4 + i) * D + nt * 16 + cl] = f2bf(acc[nt][i] * inv[i]);
    }
}

// ---------------- fused combine (MFMA) ----------------
__global__ __launch_bounds__(256) void k_combine(
    const unsigned short* Xb, const unsigned short* __restrict__ Ab,
    const float* __restrict__ Wc,
    const float* __restrict__ Wl, const float* __restrict__ bl,
    const float* __restrict__ Wg, const float* __restrict__ bg,
    const float* __restrict__ ID,
    unsigned short* Ob, float* Of, int N)
{
    __shared__ unsigned short tl[4][16][72];
    int lane = threadIdx.x & 63, w = threadIdx.x >> 6;
    int cl = lane & 15, g = lane >> 4;
    int ntiles = (N + 63) / 64;

    bf16x8 Wcf[2][4], Wlf[2][4], Wgf[2][4];
#pragma unroll
    for (int ks = 0; ks < 2; ++ks)
#pragma unroll
        for (int nt = 0; nt < 4; ++nt) {
            Wcf[ks][nt] = wfrag(Wc, ks, nt, lane);
            Wlf[ks][nt] = wfrag(Wl, ks, nt, lane);
            Wgf[ks][nt] = wfrag(Wg, ks, nt, lane);
        }
    float blv[4], bgv[4];
#pragma unroll
    for (int nt = 0; nt < 4; ++nt) {
        blv[nt] = bl[nt * 16 + cl];
        bgv[nt] = bg[nt * 16 + cl];
    }

    for (int tb = blockIdx.x; tb < ntiles; tb += gridDim.x) {
        int node0 = tb * 64 + w * 16;
        bool active = node0 < N;
        f32x4 accL[4], accG[4];
        if (active) {
            const bf16x8* xr = (const bf16x8*)(Xb + (size_t)(node0 + cl) * D + g * 8);
            const bf16x8* ar = (const bf16x8*)(Ab + (size_t)(node0 + cl) * D + g * 8);
            bf16x8 xf0 = xr[0], xf1 = xr[4];
            bf16x8 af0 = ar[0], af1 = ar[4];
            f32x4 accC[4];
#pragma unroll
            for (int nt = 0; nt < 4; ++nt) {
                f32x4 z = (f32x4){0.f, 0.f, 0.f, 0.f};
                accL[nt] = __builtin_amdgcn_mfma_f32_16x16x32_bf16(xf1, Wlf[1][nt],
                            __builtin_amdgcn_mfma_f32_16x16x32_bf16(xf0, Wlf[0][nt], z, 0, 0, 0), 0, 0, 0);
                accC[nt] = __builtin_amdgcn_mfma_f32_16x16x32_bf16(af1, Wcf[1][nt],
                            __builtin_amdgcn_mfma_f32_16x16x32_bf16(af0, Wcf[0][nt], z, 0, 0, 0), 0, 0, 0);
            }
#pragma unroll
            for (int nt = 0; nt < 4; ++nt)
#pragma unroll
                for (int i = 0; i < 4; ++i)
                    tl[w][g * 4 + i][nt * 16 + cl] = f2bf(leaky(accC[nt][i]));
        }
        __syncthreads();
        if (active) {
            const bf16x8* tr = (const bf16x8*)&tl[w][cl][g * 8];
            bf16x8 tf0 = tr[0], tf1 = tr[4];
#pragma unroll
            for (int nt = 0; nt < 4; ++nt) {
                f32x4 z = (f32x4){0.f, 0.f, 0.f, 0.f};
                accG[nt] = __builtin_amdgcn_mfma_f32_16x16x32_bf16(tf1, Wgf[1][nt],
                            __builtin_amdgcn_mfma_f32_16x16x32_bf16(tf0, Wgf[0][nt], z, 0, 0, 0), 0, 0, 0);
            }
#pragma unroll
            for (int nt = 0; nt < 4; ++nt) {
                int col = nt * 16 + cl;
#pragma unroll
                for (int i = 0; i < 4; ++i) {
                    size_t row = (size_t)(node0 + g * 4 + i);
                    float xh = leaky(accL[nt][i] + blv[nt]) + ID[row * D + col];
                    float o = leaky(accG[nt][i] + bgv[nt] + xh);
                    if (Ob) Ob[row * D + col] = f2bf(o);
                    else    Of[row * D + col] = o;
                }
            }
        }
        __syncthreads();
    }
}

extern "C" void kernel_launch(void* const* d_in, const int* in_sizes, int n_in,
                              void* d_out, int out_size, void* d_ws, size_t ws_size,
                              hipStream_t stream)
{
    const float* features = (const float*)d_in[0];
    const float* id_emb   = (const float*)d_in[1];
    const int*   eidx     = (const int*)d_in[2];
    const float* W_mlp    = (const float*)d_in[3];
    const float* b_mlp    = (const float*)d_in[4];
    const float* Wc1 = (const float*)d_in[5];
    const float* Wl1 = (const float*)d_in[6];
    const float* bl1 = (const float*)d_in[7];
    const float* Wg1 = (const float*)d_in[8];
    const float* bg1 = (const float*)d_in[9];
    const float* Wc2 = (const float*)d_in[10];
    const float* Wl2 = (const float*)d_in[11];
    const float* bl2 = (const float*)d_in[12];
    const float* Wg2 = (const float*)d_in[13];
    const float* bg2 = (const float*)d_in[14];

    int N = in_sizes[0] / D_FEAT;
    int E = in_sizes[2] / 2;
    const int* esrc = eidx;
    const int* edst = eidx + E;
    int nbk = (N + BW - 1) >> BSH;               // 782 for N=100000

    unsigned short* Xb = (unsigned short*)d_ws;  // [N][64] bf16
    unsigned short* Ab = Xb + (size_t)N * D;     // [N][64] bf16
    unsigned* pairs = (unsigned*)(Ab + (size_t)N * D);  // [E]
    int* bcnt   = (int*)(pairs + E);             // [1024]
    int* bstart = bcnt + 1024;                   // [1025]
    int* gcur   = bstart + 1025;                 // [1024]

    dim3 blk(256);
    int ntiles = (N + 63) / 64;
    int cgrid = ntiles < 512 ? ntiles : 512;
    int egrid = (E + 4095) / 4096;

    // bucket CSR build (shared by both layers)
    hipMemsetAsync(bcnt, 0, 1024 * sizeof(int), stream);
    k_bhist<<<egrid, blk, 0, stream>>>(edst, bcnt, E, nbk);
    k_bscan<<<1, 1024, 0, stream>>>(bcnt, bstart, gcur, nbk);
    k_part <<<egrid, blk, 0, stream>>>(esrc, edst, gcur, pairs, E);

    k_mlp<<<cgrid, blk, 0, stream>>>(features, W_mlp, b_mlp, Xb, N);

    // layer 1  (combine writes x1 bf16 in-place over Xb)
    k_gather <<<nbk, blk, 0, stream>>>(pairs, bstart, Xb, Ab, N);
    k_combine<<<cgrid, blk, 0, stream>>>(Xb, Ab, Wc1, Wl1, bl1, Wg1, bg1, id_emb,
                                         Xb, (float*)nullptr, N);

    // layer 2
    k_gather <<<nbk, blk, 0, stream>>>(pairs, bstart, Xb, Ab, N);
    k_combine<<<cgrid, blk, 0, stream>>>(Xb, Ab, Wc2, Wl2, bl2, Wg2, bg2, id_emb,
                                         (unsigned short*)nullptr, (float*)d_out, N);
}

// Round 6
// 232.018 us; speedup vs baseline: 6.3737x; 6.3737x over previous
//
#include <hip/hip_runtime.h>
#include <cstdint>
#include <cstddef>

#define D 64
#define D_FEAT 128
#define SLOPE 0.01f
#define BSH 7                 // bucket = dst >> 7  (128 nodes per bucket)
#define BW 128

typedef __attribute__((ext_vector_type(8))) short bf16x8;
typedef __attribute__((ext_vector_type(4))) float f32x4;

__device__ __forceinline__ float leaky(float v) { return v >= 0.f ? v : SLOPE * v; }

__device__ __forceinline__ unsigned short f2bf(float f) {
    union { float f; unsigned u; } v; v.f = f;
    unsigned r = v.u + 0x7FFF + ((v.u >> 16) & 1);   // RNE
    return (unsigned short)(r >> 16);
}
__device__ __forceinline__ float bf2f(unsigned short b) {
    union { unsigned u; float f; } v; v.u = ((unsigned)b) << 16;
    return v.f;
}

// B-fragment of row-major fp32 W[K][64] for 16x16x32 MFMA
__device__ __forceinline__ bf16x8 wfrag(const float* W, int ks, int nt, int lane) {
    int col = nt * 16 + (lane & 15);
    int k0 = ks * 32 + ((lane >> 4) << 3);
    bf16x8 r;
#pragma unroll
    for (int j = 0; j < 8; ++j)
        r[j] = (short)f2bf(W[(k0 + j) * 64 + col]);
    return r;
}

// ---------------- bucket histogram (LDS-staged) ----------------
__global__ __launch_bounds__(256) void k_bhist(const int* __restrict__ edst,
    int* __restrict__ bcnt, int E, int nbk)
{
    __shared__ int h[1024];
    for (int i = threadIdx.x; i < 1024; i += 256) h[i] = 0;
    __syncthreads();
    int base = blockIdx.x * 4096;
    for (int i = threadIdx.x; i < 4096; i += 256) {
        int e = base + i;
        if (e < E) atomicAdd(&h[edst[e] >> BSH], 1);
    }
    __syncthreads();
    for (int i = threadIdx.x; i < nbk; i += 256)
        if (h[i]) atomicAdd(&bcnt[i], h[i]);
}

// ---------------- single-block exclusive scan of bucket counts ----------------
__global__ __launch_bounds__(1024) void k_bscan(const int* __restrict__ bcnt,
    int* __restrict__ bstart, int* __restrict__ gcur,
    int* __restrict__ offs, int nbk, int Ntot)
{
    __shared__ int t[1024];
    int tid = threadIdx.x;
    int v = (tid < nbk) ? bcnt[tid] : 0;
    t[tid] = v;
    __syncthreads();
    for (int d = 1; d < 1024; d <<= 1) {
        int x = t[tid];
        int a = (tid >= d) ? t[tid - d] : 0;
        __syncthreads();
        t[tid] = x + a;
        __syncthreads();
    }
    int ex = tid ? t[tid - 1] : 0;
    if (tid < nbk) { bstart[tid] = ex; gcur[tid] = ex; }
    if (tid == 1023) { bstart[nbk] = t[1023]; offs[Ntot] = t[1023]; }
}

// ---------------- partition edges into buckets, packed (dloc<<25 | src) -------
__global__ __launch_bounds__(256) void k_part(const int* __restrict__ esrc,
    const int* __restrict__ edst, int* __restrict__ gcur,
    unsigned* __restrict__ pairs, int E)
{
    __shared__ int lcnt[1024];
    __shared__ int lbase[1024];
    int base = blockIdx.x * 4096;
    for (int i = threadIdx.x; i < 1024; i += 256) lcnt[i] = 0;
    __syncthreads();
    int dv[16];
#pragma unroll
    for (int i = 0; i < 16; ++i) {
        int e = base + i * 256 + threadIdx.x;
        if (e < E) {
            dv[i] = edst[e];
            atomicAdd(&lcnt[dv[i] >> BSH], 1);
        } else dv[i] = -1;
    }
    __syncthreads();
    for (int i = threadIdx.x; i < 1024; i += 256) {
        int c = lcnt[i];
        lbase[i] = c ? atomicAdd(&gcur[i], c) : 0;
    }
    __syncthreads();
    for (int i = threadIdx.x; i < 1024; i += 256) lcnt[i] = 0;
    __syncthreads();
#pragma unroll
    for (int i = 0; i < 16; ++i) {
        if (dv[i] >= 0) {
            int e = base + i * 256 + threadIdx.x;
            int b = dv[i] >> BSH;
            int r = atomicAdd(&lcnt[b], 1);
            unsigned pk = ((unsigned)(dv[i] & (BW - 1)) << 25) | (unsigned)esrc[e];
            pairs[lbase[b] + r] = pk;
        }
    }
}

// ---------------- per-bucket counting sort -> per-node CSR (coalesced writes) --
__global__ __launch_bounds__(256) void k_sort(const unsigned* __restrict__ pairs,
    const int* __restrict__ bstart, int* __restrict__ offs,
    int* __restrict__ srcs, int N)
{
    __shared__ int lh[BW];
    __shared__ int cur[BW];
    __shared__ unsigned buf[4096];
    int b = blockIdx.x;
    int node0 = b << BSH;
    int s0 = bstart[b], s1 = bstart[b + 1];
    int cnt = s1 - s0;
    if (threadIdx.x < BW) lh[threadIdx.x] = 0;
    __syncthreads();
    for (int i = threadIdx.x; i < cnt; i += 256)
        atomicAdd(&lh[pairs[s0 + i] >> 25], 1);
    __syncthreads();
    if (threadIdx.x < 64) {   // wave 0: exclusive scan of 128 counts, 2/lane
        int a = lh[2 * threadIdx.x], c = lh[2 * threadIdx.x + 1];
        int s = a + c, inc = s;
#pragma unroll
        for (int d = 1; d < 64; d <<= 1) {
            int u = __shfl_up(inc, d);
            if ((int)threadIdx.x >= d) inc += u;
        }
        int ex = inc - s;
        cur[2 * threadIdx.x] = ex;
        cur[2 * threadIdx.x + 1] = ex + a;
    }
    __syncthreads();
    if (threadIdx.x < BW) {
        int node = node0 + threadIdx.x;
        if (node < N) offs[node] = s0 + cur[threadIdx.x];
    }
    __syncthreads();
    if (cnt <= 4096) {
        for (int i = threadIdx.x; i < cnt; i += 256) {
            unsigned p = pairs[s0 + i];
            int r = atomicAdd(&cur[p >> 25], 1);
            buf[r] = p & 0x1FFFFFFu;
        }
        __syncthreads();
        for (int i = threadIdx.x; i < cnt; i += 256)
            srcs[s0 + i] = (int)buf[i];
    } else {   // statistically unreachable fallback (Poisson mean ~2046)
        for (int i = threadIdx.x; i < cnt; i += 256) {
            unsigned p = pairs[s0 + i];
            int r = atomicAdd(&cur[p >> 25], 1);
            srcs[s0 + r] = (int)(p & 0x1FFFFFFu);
        }
    }
}

// ---------------- MLP + L2 norm (MFMA), fp32 in -> bf16 out ----------------
__global__ __launch_bounds__(256) void k_mlp(const float* __restrict__ F,
    const float* __restrict__ Wm, const float* __restrict__ bm,
    unsigned short* __restrict__ Xb, int N)
{
    int lane = threadIdx.x & 63, w = threadIdx.x >> 6;
    int cl = lane & 15, g = lane >> 4;
    int ntiles = (N + 63) / 64;

    bf16x8 Wmf[4][4];
#pragma unroll
    for (int ks = 0; ks < 4; ++ks)
#pragma unroll
        for (int nt = 0; nt < 4; ++nt)
            Wmf[ks][nt] = wfrag(Wm, ks, nt, lane);
    float bmv[4];
#pragma unroll
    for (int nt = 0; nt < 4; ++nt) bmv[nt] = bm[nt * 16 + cl];

    for (int tb = blockIdx.x; tb < ntiles; tb += gridDim.x) {
        int node0 = tb * 64 + w * 16;
        if (node0 >= N) continue;
        f32x4 acc[4];
#pragma unroll
        for (int nt = 0; nt < 4; ++nt) acc[nt] = (f32x4){0.f, 0.f, 0.f, 0.f};
#pragma unroll
        for (int ks = 0; ks < 4; ++ks) {
            const float4* fp = (const float4*)(F + (size_t)(node0 + cl) * D_FEAT + ks * 32 + g * 8);
            float4 a = fp[0], b = fp[1];
            bf16x8 af;
            af[0] = (short)f2bf(a.x); af[1] = (short)f2bf(a.y);
            af[2] = (short)f2bf(a.z); af[3] = (short)f2bf(a.w);
            af[4] = (short)f2bf(b.x); af[5] = (short)f2bf(b.y);
            af[6] = (short)f2bf(b.z); af[7] = (short)f2bf(b.w);
#pragma unroll
            for (int nt = 0; nt < 4; ++nt)
                acc[nt] = __builtin_amdgcn_mfma_f32_16x16x32_bf16(af, Wmf[ks][nt], acc[nt], 0, 0, 0);
        }
        float ss[4] = {0.f, 0.f, 0.f, 0.f};
#pragma unroll
        for (int nt = 0; nt < 4; ++nt)
#pragma unroll
            for (int i = 0; i < 4; ++i) {
                float v = acc[nt][i] + bmv[nt];
                acc[nt][i] = v;
                ss[i] += v * v;
            }
#pragma unroll
        for (int off = 8; off >= 1; off >>= 1)
#pragma unroll
            for (int i = 0; i < 4; ++i)
                ss[i] += __shfl_xor(ss[i], off);
        float inv[4];
#pragma unroll
        for (int i = 0; i < 4; ++i)
            inv[i] = 1.f / fmaxf(sqrtf(ss[i]), 1e-12f);
#pragma unroll
        for (int nt = 0; nt < 4; ++nt)
#pragma unroll
            for (int i = 0; i < 4; ++i)
                Xb[(size_t)(node0 + g * 4 + i) * D + nt * 16 + cl] = f2bf(acc[nt][i] * inv[i]);
    }
}

// ---------------- gather: Agg[n] = sum_{edges dst==n} Xb[src] ----------------
// quarter-wave per edge: 16 lanes x 8B cover one 64xbf16 row; 4 edges/iter
__global__ __launch_bounds__(256) void k_gather(const int* __restrict__ offs,
    const int* __restrict__ srcs, const unsigned short* __restrict__ Xb,
    unsigned short* __restrict__ Ab, int N)
{
    int lane = threadIdx.x & 63, w = threadIdx.x >> 6;
    int node = blockIdx.x * 4 + w;
    if (node >= N) return;
    int start = offs[node];
    int end = offs[node + 1];
    int q = lane >> 4;
    int c4 = (lane & 15) * 4;
    float4 acc = {0.f, 0.f, 0.f, 0.f};
    for (int base = start; base < end; base += 64) {
        int m = end - base; if (m > 64) m = 64;
        int sid = (base + lane < end) ? srcs[base + lane] : 0;
        int iters = (m + 3) >> 2;
        for (int j = 0; j < iters; ++j) {
            int idx = (j << 2) | q;
            int s = __shfl(sid, idx);
            if (idx < m) {
                uint2 u = *(const uint2*)(Xb + (size_t)s * D + c4);
                acc.x += bf2f((unsigned short)(u.x & 0xFFFFu));
                acc.y += bf2f((unsigned short)(u.x >> 16));
                acc.z += bf2f((unsigned short)(u.y & 0xFFFFu));
                acc.w += bf2f((unsigned short)(u.y >> 16));
            }
        }
    }
#pragma unroll
    for (int d = 32; d >= 16; d >>= 1) {
        acc.x += __shfl_xor(acc.x, d);
        acc.y += __shfl_xor(acc.y, d);
        acc.z += __shfl_xor(acc.z, d);
        acc.w += __shfl_xor(acc.w, d);
    }
    if (q == 0) {
        uint2 o;
        o.x = (unsigned)f2bf(acc.x) | ((unsigned)f2bf(acc.y) << 16);
        o.y = (unsigned)f2bf(acc.z) | ((unsigned)f2bf(acc.w) << 16);
        *(uint2*)(Ab + (size_t)node * D + c4) = o;
    }
}

// ---------------- fused combine (MFMA):
// O = leaky( leaky(Agg@Wc)@Wg + bg + leaky(X@Wl + bl) + ID ) ----------------
__global__ __launch_bounds__(256) void k_combine(
    const unsigned short* Xb, const unsigned short* __restrict__ Ab,
    const float* __restrict__ Wc,
    const float* __restrict__ Wl, const float* __restrict__ bl,
    const float* __restrict__ Wg, const float* __restrict__ bg,
    const float* __restrict__ ID,
    unsigned short* Ob, float* Of, int N)
{
    __shared__ unsigned short tl[4][16][72];
    int lane = threadIdx.x & 63, w = threadIdx.x >> 6;
    int cl = lane & 15, g = lane >> 4;
    int ntiles = (N + 63) / 64;

    bf16x8 Wcf[2][4], Wlf[2][4], Wgf[2][4];
#pragma unroll
    for (int ks = 0; ks < 2; ++ks)
#pragma unroll
        for (int nt = 0; nt < 4; ++nt) {
            Wcf[ks][nt] = wfrag(Wc, ks, nt, lane);
            Wlf[ks][nt] = wfrag(Wl, ks, nt, lane);
            Wgf[ks][nt] = wfrag(Wg, ks, nt, lane);
        }
    float blv[4], bgv[4];
#pragma unroll
    for (int nt = 0; nt < 4; ++nt) {
        blv[nt] = bl[nt * 16 + cl];
        bgv[nt] = bg[nt * 16 + cl];
    }

    for (int tb = blockIdx.x; tb < ntiles; tb += gridDim.x) {
        int node0 = tb * 64 + w * 16;
        bool active = node0 < N;
        f32x4 accL[4], accG[4];
        if (active) {
            const bf16x8* xr = (const bf16x8*)(Xb + (size_t)(node0 + cl) * D + g * 8);
            const bf16x8* ar = (const bf16x8*)(Ab + (size_t)(node0 + cl) * D + g * 8);
            bf16x8 xf0 = xr[0], xf1 = xr[4];
            bf16x8 af0 = ar[0], af1 = ar[4];
            f32x4 accC[4];
#pragma unroll
            for (int nt = 0; nt < 4; ++nt) {
                f32x4 z = (f32x4){0.f, 0.f, 0.f, 0.f};
                accL[nt] = __builtin_amdgcn_mfma_f32_16x16x32_bf16(xf1, Wlf[1][nt],
                            __builtin_amdgcn_mfma_f32_16x16x32_bf16(xf0, Wlf[0][nt], z, 0, 0, 0), 0, 0, 0);
                accC[nt] = __builtin_amdgcn_mfma_f32_16x16x32_bf16(af1, Wcf[1][nt],
                            __builtin_amdgcn_mfma_f32_16x16x32_bf16(af0, Wcf[0][nt], z, 0, 0, 0), 0, 0, 0);
            }
#pragma unroll
            for (int nt = 0; nt < 4; ++nt)
#pragma unroll
                for (int i = 0; i < 4; ++i)
                    tl[w][g * 4 + i][nt * 16 + cl] = f2bf(leaky(accC[nt][i]));
        }
        __syncthreads();
        if (active) {
            const bf16x8* tr = (const bf16x8*)&tl[w][cl][g * 8];
            bf16x8 tf0 = tr[0], tf1 = tr[4];
#pragma unroll
            for (int nt = 0; nt < 4; ++nt) {
                f32x4 z = (f32x4){0.f, 0.f, 0.f, 0.f};
                accG[nt] = __builtin_amdgcn_mfma_f32_16x16x32_bf16(tf1, Wgf[1][nt],
                            __builtin_amdgcn_mfma_f32_16x16x32_bf16(tf0, Wgf[0][nt], z, 0, 0, 0), 0, 0, 0);
            }
#pragma unroll
            for (int nt = 0; nt < 4; ++nt) {
                int col = nt * 16 + cl;
#pragma unroll
                for (int i = 0; i < 4; ++i) {
                    size_t row = (size_t)(node0 + g * 4 + i);
                    float xh = leaky(accL[nt][i] + blv[nt]) + ID[row * D + col];
                    float o = leaky(accG[nt][i] + bgv[nt] + xh);
                    if (Ob) Ob[row * D + col] = f2bf(o);
                    else    Of[row * D + col] = o;
                }
            }
        }
        __syncthreads();
    }
}

extern "C" void kernel_launch(void* const* d_in, const int* in_sizes, int n_in,
                              void* d_out, int out_size, void* d_ws, size_t ws_size,
                              hipStream_t stream)
{
    const float* features = (const float*)d_in[0];
    const float* id_emb   = (const float*)d_in[1];
    const int*   eidx     = (const int*)d_in[2];
    const float* W_mlp    = (const float*)d_in[3];
    const float* b_mlp    = (const float*)d_in[4];
    const float* Wc1 = (const float*)d_in[5];
    const float* Wl1 = (const float*)d_in[6];
    const float* bl1 = (const float*)d_in[7];
    const float* Wg1 = (const float*)d_in[8];
    const float* bg1 = (const float*)d_in[9];
    const float* Wc2 = (const float*)d_in[10];
    const float* Wl2 = (const float*)d_in[11];
    const float* bl2 = (const float*)d_in[12];
    const float* Wg2 = (const float*)d_in[13];
    const float* bg2 = (const float*)d_in[14];

    int N = in_sizes[0] / D_FEAT;
    int E = in_sizes[2] / 2;
    const int* esrc = eidx;
    const int* edst = eidx + E;
    int nbk = (N + BW - 1) >> BSH;               // 782 for N=100000

    unsigned short* Xb = (unsigned short*)d_ws;  // [N][64] bf16
    unsigned short* Ab = Xb + (size_t)N * D;     // [N][64] bf16
    int* srcs   = (int*)(Ab + (size_t)N * D);    // [E]
    int* offs   = srcs + E;                      // [N+1]
    int* bcnt   = offs + N + 1;                  // [1024]
    int* bstart = bcnt + 1024;                   // [1025]
    int* gcur   = bstart + 1025;                 // [1024]

    // pairs scratch lives in d_out (25.6 MB fp32 out >= 6.4 MB); it is fully
    // dead before the final combine writes d_out.
    unsigned* pairs = (unsigned*)d_out;

    dim3 blk(256);
    int ntiles = (N + 63) / 64;
    int cgrid = ntiles < 512 ? ntiles : 512;
    int egrid = (E + 4095) / 4096;

    // bucket CSR build (shared by both layers)
    hipMemsetAsync(bcnt, 0, 1024 * sizeof(int), stream);
    k_bhist<<<egrid, blk, 0, stream>>>(edst, bcnt, E, nbk);
    k_bscan<<<1, 1024, 0, stream>>>(bcnt, bstart, gcur, offs, nbk, N);
    k_part <<<egrid, blk, 0, stream>>>(esrc, edst, gcur, pairs, E);
    k_sort <<<nbk, blk, 0, stream>>>(pairs, bstart, offs, srcs, N);

    k_mlp<<<cgrid, blk, 0, stream>>>(features, W_mlp, b_mlp, Xb, N);

    // layer 1  (combine writes x1 bf16 in-place over Xb)
    k_gather <<<(N + 3) / 4, blk, 0, stream>>>(offs, srcs, Xb, Ab, N);
    k_combine<<<cgrid, blk, 0, stream>>>(Xb, Ab, Wc1, Wl1, bl1, Wg1, bg1, id_emb,
                                         Xb, (float*)nullptr, N);

    // layer 2
    k_gather <<<(N + 3) / 4, blk, 0, stream>>>(offs, srcs, Xb, Ab, N);
    k_combine<<<cgrid, blk, 0, stream>>>(Xb, Ab, Wc2, Wl2, bl2, Wg2, bg2, id_emb,
                                         (unsigned short*)nullptr, (float*)d_out, N);
}